// Round 5
// baseline (96.552 us; speedup 1.0000x reference)
//
#include <hip/hip_runtime.h>

// SSIM loss, 7x7 uniform window, VALID, over (64,1,512,512) fp32.
// Fused single-pass separable box sums.
// R4 changes vs R0: SH 64->32 (2048 blocks -> 8 blocks/CU, occupancy 2x),
// software-pipelined row prefetch (loads for row r+1 issue under row r's
// compute), fast reciprocal (v_rcp_f32 + 1 NR) instead of fp32 divide.

constexpr int B  = 64;
constexpr int H  = 512, W = 512;
constexpr int OH = H - 6, OW = W - 6;     // 506
constexpr int TW = 256;                   // output tile width == blockDim.x
constexpr int SH = 32;                    // output strip height per block

constexpr float INV_NP    = 1.0f / 49.0f;
constexpr float COV_NORM  = 49.0f / 48.0f;

__global__ __launch_bounds__(256, 8)      // pin VGPR <= 64 for 8 waves/SIMD
void ssim_main(const float* __restrict__ X, const float* __restrict__ Y,
               const float* __restrict__ DR, float* __restrict__ partials)
{
    const int tid   = threadIdx.x;
    const int tilex = blockIdx.x;   // 0..1
    const int strip = blockIdx.y;   // 0..15
    const int b     = blockIdx.z;   // 0..63

    const int cb = tilex * TW;
    const int r0 = strip * SH;
    const int out_rows = min(SH, OH - r0);
    const int rows_in  = out_rows + 6;          // input rows this strip needs

    const float d  = DR[b];
    const float C1 = (0.01f * d) * (0.01f * d);
    const float C2 = (0.03f * d) * (0.03f * d);

    const float* __restrict__ Xb = X + (size_t)b * H * W;
    const float* __restrict__ Yb = Y + (size_t)b * H * W;

    // double-buffered input row: {x, y} pairs, 262 used
    __shared__ float2 rb[2][TW + 8];

    const bool colvalid = (cb + tid) < OW;
    const bool halo_ok  = (tid < 6) && (cb + TW + tid < W);

    // vertical circular buffers (statically indexed via 7x unroll)
    float bx[7], by[7], bxx[7], byy[7], bxy[7];
    float vsx = 0.f, vsy = 0.f, vsxx = 0.f, vsyy = 0.f, vsxy = 0.f;
#pragma unroll
    for (int i = 0; i < 7; ++i) { bx[i]=by[i]=bxx[i]=byy[i]=bxy[i]=0.f; }

    float acc = 0.f;

    // prefetch registers for the next input row
    float2 pre  = make_float2(0.f, 0.f);
    float2 preh = make_float2(0.f, 0.f);
    {
        const float* xrow = Xb + r0 * W + cb;
        const float* yrow = Yb + r0 * W + cb;
        pre = make_float2(xrow[tid], yrow[tid]);
        if (tid < 6)
            preh = halo_ok ? make_float2(xrow[TW + tid], yrow[TW + tid])
                           : make_float2(0.f, 0.f);
    }

    for (int rr = 0; rr < 42; rr += 7) {        // covers rows_in <= 38
#pragma unroll
        for (int p = 0; p < 7; ++p) {
            const int r = rr + p;                  // r % 7 == p (rr multiple of 7)
            if (r < rows_in) {                     // block-uniform condition
                float2* buf = rb[r & 1];
                buf[tid] = pre;
                if (tid < 6) buf[TW + tid] = preh;
                __syncthreads();

                // issue next row's global loads now; s_waitcnt lands at next
                // iteration's LDS write, so latency hides under compute below
                if (r + 1 < rows_in) {
                    const int in_row = r0 + r + 1;
                    const float* xrow = Xb + in_row * W + cb;
                    const float* yrow = Yb + in_row * W + cb;
                    pre = make_float2(xrow[tid], yrow[tid]);
                    if (tid < 6)
                        preh = halo_ok ? make_float2(xrow[TW + tid], yrow[TW + tid])
                                       : make_float2(0.f, 0.f);
                }

                // horizontal 7-tap sums of the 5 channels
                float hx = 0.f, hy = 0.f, hxx = 0.f, hyy = 0.f, hxy = 0.f;
#pragma unroll
                for (int i = 0; i < 7; ++i) {
                    const float2 v = buf[tid + i];
                    hx += v.x; hy += v.y;
                    hxx = fmaf(v.x, v.x, hxx);
                    hyy = fmaf(v.y, v.y, hyy);
                    hxy = fmaf(v.x, v.y, hxy);
                }

                // vertical running 7-row window (slot p holds row r-7's value)
                vsx  += hx  - bx[p];  bx[p]  = hx;
                vsy  += hy  - by[p];  by[p]  = hy;
                vsxx += hxx - bxx[p]; bxx[p] = hxx;
                vsyy += hyy - byy[p]; byy[p] = hyy;
                vsxy += hxy - bxy[p]; bxy[p] = hxy;

                if (r >= 6 && colvalid) {
                    const float ux  = vsx  * INV_NP;
                    const float uy  = vsy  * INV_NP;
                    const float uxx = vsxx * INV_NP;
                    const float uyy = vsyy * INV_NP;
                    const float uxy = vsxy * INV_NP;
                    const float vx  = COV_NORM * (uxx - ux * ux);
                    const float vy  = COV_NORM * (uyy - uy * uy);
                    const float vxy = COV_NORM * (uxy - ux * uy);
                    const float A1 = 2.f * ux * uy + C1;
                    const float A2 = 2.f * vxy + C2;
                    const float B1 = ux * ux + uy * uy + C1;
                    const float B2 = vx + vy + C2;
                    const float den = B1 * B2;
                    float rcp = __builtin_amdgcn_rcpf(den);
                    rcp = rcp * (2.f - den * rcp);      // 1 Newton step
                    acc = fmaf(A1 * A2, rcp, acc);
                }
            }
        }
    }

    // block reduction: wave shfl, then cross-wave via LDS
    float s = acc;
#pragma unroll
    for (int off = 32; off; off >>= 1) s += __shfl_down(s, off, 64);
    __shared__ float wsum[4];
    if ((tid & 63) == 0) wsum[tid >> 6] = s;
    __syncthreads();
    if (tid == 0) {
        const int bid = (blockIdx.z * gridDim.y + blockIdx.y) * gridDim.x + blockIdx.x;
        partials[bid] = wsum[0] + wsum[1] + wsum[2] + wsum[3];
    }
}

__global__ __launch_bounds__(256)
void ssim_final(const float* __restrict__ partials, int n,
                float* __restrict__ out, float inv_count)
{
    const int tid = threadIdx.x;
    float s = 0.f;
    for (int i = tid; i < n; i += 256) s += partials[i];
#pragma unroll
    for (int off = 32; off; off >>= 1) s += __shfl_down(s, off, 64);
    __shared__ float wsum[4];
    if ((tid & 63) == 0) wsum[tid >> 6] = s;
    __syncthreads();
    if (tid == 0) out[0] = 1.0f - (wsum[0] + wsum[1] + wsum[2] + wsum[3]) * inv_count;
}

extern "C" void kernel_launch(void* const* d_in, const int* in_sizes, int n_in,
                              void* d_out, int out_size, void* d_ws, size_t ws_size,
                              hipStream_t stream)
{
    const float* X  = (const float*)d_in[0];
    const float* Y  = (const float*)d_in[1];
    const float* DR = (const float*)d_in[2];
    float* out      = (float*)d_out;
    float* partials = (float*)d_ws;

    const int gx = (OW + TW - 1) / TW;   // 2
    const int gy = (OH + SH - 1) / SH;   // 16
    dim3 grid(gx, gy, B);                // 2048 blocks, every partial slot written
    ssim_main<<<grid, 256, 0, stream>>>(X, Y, DR, partials);

    const int n = gx * gy * B;
    const float inv_count = 1.0f / (float)((long)B * OH * OW);
    ssim_final<<<1, 256, 0, stream>>>(partials, n, out, inv_count);
}

// Round 6
// 50.451 us; speedup vs baseline: 1.9138x; 1.9138x over previous
//
#include <hip/hip_runtime.h>

// SSIM loss, 7x7 uniform window, VALID, over (64,1,512,512) fp32.
// Fused single-pass separable box sums.
// R6 = R5 minus the __launch_bounds__(256,8) VGPR pin (it forced VGPR=32 and
// spilled the circular buffers: WRITE_SIZE 32KB -> 143MB). Keep: SH=32 grid
// (8 wg/CU, occupancy 84%), row prefetch, fast rcp.

constexpr int B  = 64;
constexpr int H  = 512, W = 512;
constexpr int OH = H - 6, OW = W - 6;     // 506
constexpr int TW = 256;                   // output tile width == blockDim.x
constexpr int SH = 32;                    // output strip height per block

constexpr float INV_NP    = 1.0f / 49.0f;
constexpr float COV_NORM  = 49.0f / 48.0f;

__global__ __launch_bounds__(256)         // no min-wave pin: VGPR ~50 < 64 keeps 8 waves/SIMD
void ssim_main(const float* __restrict__ X, const float* __restrict__ Y,
               const float* __restrict__ DR, float* __restrict__ partials)
{
    const int tid   = threadIdx.x;
    const int tilex = blockIdx.x;   // 0..1
    const int strip = blockIdx.y;   // 0..15
    const int b     = blockIdx.z;   // 0..63

    const int cb = tilex * TW;
    const int r0 = strip * SH;
    const int out_rows = min(SH, OH - r0);
    const int rows_in  = out_rows + 6;          // input rows this strip needs

    const float d  = DR[b];
    const float C1 = (0.01f * d) * (0.01f * d);
    const float C2 = (0.03f * d) * (0.03f * d);

    const float* __restrict__ Xb = X + (size_t)b * H * W;
    const float* __restrict__ Yb = Y + (size_t)b * H * W;

    // double-buffered input row: {x, y} pairs, 262 used
    __shared__ float2 rb[2][TW + 8];

    const bool colvalid = (cb + tid) < OW;
    const bool halo_ok  = (tid < 6) && (cb + TW + tid < W);

    // vertical circular buffers (statically indexed via 7x unroll)
    float bx[7], by[7], bxx[7], byy[7], bxy[7];
    float vsx = 0.f, vsy = 0.f, vsxx = 0.f, vsyy = 0.f, vsxy = 0.f;
#pragma unroll
    for (int i = 0; i < 7; ++i) { bx[i]=by[i]=bxx[i]=byy[i]=bxy[i]=0.f; }

    float acc = 0.f;

    // prefetch registers for the next input row
    float2 pre  = make_float2(0.f, 0.f);
    float2 preh = make_float2(0.f, 0.f);
    {
        const float* xrow = Xb + r0 * W + cb;
        const float* yrow = Yb + r0 * W + cb;
        pre = make_float2(xrow[tid], yrow[tid]);
        if (tid < 6)
            preh = halo_ok ? make_float2(xrow[TW + tid], yrow[TW + tid])
                           : make_float2(0.f, 0.f);
    }

    for (int rr = 0; rr < 42; rr += 7) {        // covers rows_in <= 38
#pragma unroll
        for (int p = 0; p < 7; ++p) {
            const int r = rr + p;                  // r % 7 == p (rr multiple of 7)
            if (r < rows_in) {                     // block-uniform condition
                float2* buf = rb[r & 1];
                buf[tid] = pre;
                if (tid < 6) buf[TW + tid] = preh;
                __syncthreads();

                // issue next row's global loads now; s_waitcnt lands at next
                // iteration's LDS write, so latency hides under compute below
                if (r + 1 < rows_in) {
                    const int in_row = r0 + r + 1;
                    const float* xrow = Xb + in_row * W + cb;
                    const float* yrow = Yb + in_row * W + cb;
                    pre = make_float2(xrow[tid], yrow[tid]);
                    if (tid < 6)
                        preh = halo_ok ? make_float2(xrow[TW + tid], yrow[TW + tid])
                                       : make_float2(0.f, 0.f);
                }

                // horizontal 7-tap sums of the 5 channels
                float hx = 0.f, hy = 0.f, hxx = 0.f, hyy = 0.f, hxy = 0.f;
#pragma unroll
                for (int i = 0; i < 7; ++i) {
                    const float2 v = buf[tid + i];
                    hx += v.x; hy += v.y;
                    hxx = fmaf(v.x, v.x, hxx);
                    hyy = fmaf(v.y, v.y, hyy);
                    hxy = fmaf(v.x, v.y, hxy);
                }

                // vertical running 7-row window (slot p holds row r-7's value)
                vsx  += hx  - bx[p];  bx[p]  = hx;
                vsy  += hy  - by[p];  by[p]  = hy;
                vsxx += hxx - bxx[p]; bxx[p] = hxx;
                vsyy += hyy - byy[p]; byy[p] = hyy;
                vsxy += hxy - bxy[p]; bxy[p] = hxy;

                if (r >= 6 && colvalid) {
                    const float ux  = vsx  * INV_NP;
                    const float uy  = vsy  * INV_NP;
                    const float uxx = vsxx * INV_NP;
                    const float uyy = vsyy * INV_NP;
                    const float uxy = vsxy * INV_NP;
                    const float vx  = COV_NORM * (uxx - ux * ux);
                    const float vy  = COV_NORM * (uyy - uy * uy);
                    const float vxy = COV_NORM * (uxy - ux * uy);
                    const float A1 = 2.f * ux * uy + C1;
                    const float A2 = 2.f * vxy + C2;
                    const float B1 = ux * ux + uy * uy + C1;
                    const float B2 = vx + vy + C2;
                    const float den = B1 * B2;
                    float rcp = __builtin_amdgcn_rcpf(den);
                    rcp = rcp * (2.f - den * rcp);      // 1 Newton step
                    acc = fmaf(A1 * A2, rcp, acc);
                }
            }
        }
    }

    // block reduction: wave shfl, then cross-wave via LDS
    float s = acc;
#pragma unroll
    for (int off = 32; off; off >>= 1) s += __shfl_down(s, off, 64);
    __shared__ float wsum[4];
    if ((tid & 63) == 0) wsum[tid >> 6] = s;
    __syncthreads();
    if (tid == 0) {
        const int bid = (blockIdx.z * gridDim.y + blockIdx.y) * gridDim.x + blockIdx.x;
        partials[bid] = wsum[0] + wsum[1] + wsum[2] + wsum[3];
    }
}

__global__ __launch_bounds__(256)
void ssim_final(const float* __restrict__ partials, int n,
                float* __restrict__ out, float inv_count)
{
    const int tid = threadIdx.x;
    float s = 0.f;
    for (int i = tid; i < n; i += 256) s += partials[i];
#pragma unroll
    for (int off = 32; off; off >>= 1) s += __shfl_down(s, off, 64);
    __shared__ float wsum[4];
    if ((tid & 63) == 0) wsum[tid >> 6] = s;
    __syncthreads();
    if (tid == 0) out[0] = 1.0f - (wsum[0] + wsum[1] + wsum[2] + wsum[3]) * inv_count;
}

extern "C" void kernel_launch(void* const* d_in, const int* in_sizes, int n_in,
                              void* d_out, int out_size, void* d_ws, size_t ws_size,
                              hipStream_t stream)
{
    const float* X  = (const float*)d_in[0];
    const float* Y  = (const float*)d_in[1];
    const float* DR = (const float*)d_in[2];
    float* out      = (float*)d_out;
    float* partials = (float*)d_ws;

    const int gx = (OW + TW - 1) / TW;   // 2
    const int gy = (OH + SH - 1) / SH;   // 16
    dim3 grid(gx, gy, B);                // 2048 blocks, every partial slot written
    ssim_main<<<grid, 256, 0, stream>>>(X, Y, DR, partials);

    const int n = gx * gy * B;
    const float inv_count = 1.0f / (float)((long)B * OH * OW);
    ssim_final<<<1, 256, 0, stream>>>(partials, n, out, inv_count);
}